// Round 3
// baseline (42905.002 us; speedup 1.0000x reference)
//
#include <hip/hip_runtime.h>

#define TT 1024
#define HH 256
#define EE 64
#define NC 10

// One block per batch row (128 blocks x 1024 threads). The LSTM recurrence is
// independent per batch row, so there is NO cross-block sync: h lives in LDS
// (double-buffered), weights live in VGPRs (thread (j,kq) holds
// W_g[kq*64 .. kq*64+63][j] for all 4 gates = 256 VGPRs), and each step costs
// one __syncthreads. fp32 VALU floor: 2048 cyc/step/CU -> ~874us total.

__global__ __launch_bounds__(1024, 1) void lstm_rowblock(
    const int* __restrict__ x, const float* __restrict__ emb,
    const float* __restrict__ Wfx, const float* __restrict__ Wfh, const float* __restrict__ bf_,
    const float* __restrict__ Wix, const float* __restrict__ Wih, const float* __restrict__ bi_,
    const float* __restrict__ Wgx, const float* __restrict__ Wgh, const float* __restrict__ bg_,
    const float* __restrict__ Wox, const float* __restrict__ Woh, const float* __restrict__ bo_,
    const float* __restrict__ Wph, const float* __restrict__ Wpb,
    float* __restrict__ out)
{
  const int tid = threadIdx.x;
  const int b   = blockIdx.x;          // batch row
  const int j   = tid >> 2;            // output column 0..255
  const int kq  = tid & 3;             // k-quarter 0..3
  const int kq68 = kq * 68;            // padded LDS base: f(k)=k+((k>>6)<<2)
  const int jpad = j + ((j >> 6) << 2);

  __shared__ __align__(16) float hb0[272];
  __shared__ __align__(16) float hb1[272];
  __shared__ float xp[3 * 4 * HH];     // [vocab][gate][j], bias folded
  __shared__ int   xs[TT];
  __shared__ float pj[NC];

  // x row -> LDS (one step's index read per t, uniform broadcast later)
  xs[tid] = x[b * TT + tid];

  // x-projection table: 3 vocab x 4 gates x 256 cols
  for (int idx = tid; idx < 3 * 4 * HH; idx += 1024) {
    int v = idx >> 10, r = idx & 1023, g = r >> 8, jj = r & 255;
    const float* Wx = (g == 0) ? Wfx : (g == 1) ? Wix : (g == 2) ? Wgx : Wox;
    const float* bb = (g == 0) ? bf_ : (g == 1) ? bi_ : (g == 2) ? bg_ : bo_;
    float a = bb[jj];
    const float* ev = emb + v * EE;
#pragma unroll 16
    for (int e = 0; e < EE; ++e) a = fmaf(ev[e], Wx[e * HH + jj], a);
    xp[idx] = a;
  }

  // recurrent weights -> VGPRs (static indices only; must not spill)
  float wreg[256];
  {
#pragma unroll
    for (int g = 0; g < 4; ++g) {
      const float* Wg = (g == 0) ? Wfh : (g == 1) ? Wih : (g == 2) ? Wgh : Woh;
      const float* wp = Wg + (kq * 64) * HH + j;
#pragma unroll
      for (int kk = 0; kk < 64; ++kk) wreg[g * 64 + kk] = wp[kk * HH];
    }
  }

  if (tid < 272) { hb0[tid] = 0.f; hb1[tid] = 0.f; }
  float creg = 0.f;
  __syncthreads();

  auto step = [&](const float* __restrict__ hR, float* __restrict__ hW, int t) {
    const int v = xs[t];                       // uniform
    const float* hq = hR + kq68;
    float a0 = 0.f, a1 = 0.f, a2 = 0.f, a3 = 0.f;
#pragma unroll
    for (int k4 = 0; k4 < 16; ++k4) {
      const float4 hv = *(const float4*)(hq + k4 * 4);
      const int kb = k4 * 4;
      a0 = fmaf(hv.x, wreg[kb + 0], a0);
      a0 = fmaf(hv.y, wreg[kb + 1], a0);
      a0 = fmaf(hv.z, wreg[kb + 2], a0);
      a0 = fmaf(hv.w, wreg[kb + 3], a0);
      a1 = fmaf(hv.x, wreg[64 + kb + 0], a1);
      a1 = fmaf(hv.y, wreg[64 + kb + 1], a1);
      a1 = fmaf(hv.z, wreg[64 + kb + 2], a1);
      a1 = fmaf(hv.w, wreg[64 + kb + 3], a1);
      a2 = fmaf(hv.x, wreg[128 + kb + 0], a2);
      a2 = fmaf(hv.y, wreg[128 + kb + 1], a2);
      a2 = fmaf(hv.z, wreg[128 + kb + 2], a2);
      a2 = fmaf(hv.w, wreg[128 + kb + 3], a2);
      a3 = fmaf(hv.x, wreg[192 + kb + 0], a3);
      a3 = fmaf(hv.y, wreg[192 + kb + 1], a3);
      a3 = fmaf(hv.z, wreg[192 + kb + 2], a3);
      a3 = fmaf(hv.w, wreg[192 + kb + 3], a3);
    }
    // reduce across the 4 kq lanes (DPP quad-perm shuffles)
    a0 += __shfl_xor(a0, 1, 64); a0 += __shfl_xor(a0, 2, 64);
    a1 += __shfl_xor(a1, 1, 64); a1 += __shfl_xor(a1, 2, 64);
    a2 += __shfl_xor(a2, 1, 64); a2 += __shfl_xor(a2, 2, 64);
    a3 += __shfl_xor(a3, 1, 64); a3 += __shfl_xor(a3, 2, 64);

    // gates (all 4 kq lanes compute identically; only kq==0 writes)
    const float* xpv = xp + v * (4 * HH) + j;
    float pf = a0 + xpv[0 * HH];
    float pi = a1 + xpv[1 * HH];
    float pg = a2 + xpv[2 * HH];
    float po = a3 + xpv[3 * HH];
    float f = __fdividef(1.f, 1.f + __expf(-pf));
    float i = __fdividef(1.f, 1.f + __expf(-pi));
    float o = __fdividef(1.f, 1.f + __expf(-po));
    float gx = fminf(15.f, fmaxf(-15.f, pg));
    float eg = __expf(2.f * gx);
    float g = __fdividef(eg - 1.f, eg + 1.f);
    creg = f * creg + i * g;
    float cx = fminf(15.f, fmaxf(-15.f, creg));
    float ec = __expf(2.f * cx);
    float th = __fdividef(ec - 1.f, ec + 1.f);
    if (kq == 0) hW[jpad] = th * o;
    __syncthreads();
  };

  for (int t2 = 0; t2 < TT; t2 += 2) {
    step(hb0, hb1, t2);       // even t: read hb0, write hb1
    step(hb1, hb0, t2 + 1);   // odd  t: read hb1, write hb0
  }

  // final h is in hb0 (t=1023 wrote hb0). Projection + log_softmax.
  if (tid < NC) {
    float a = Wpb[tid];
    for (int k = 0; k < HH; ++k)
      a = fmaf(hb0[k + ((k >> 6) << 2)], Wph[k * NC + tid], a);
    pj[tid] = a;
  }
  __syncthreads();
  if (tid < NC) {
    float m = pj[0];
#pragma unroll
    for (int c2 = 1; c2 < NC; ++c2) m = fmaxf(m, pj[c2]);
    float s = 0.f;
#pragma unroll
    for (int c2 = 0; c2 < NC; ++c2) s += __expf(pj[c2] - m);
    out[b * NC + tid] = pj[tid] - m - __logf(s);
  }
}

extern "C" void kernel_launch(void* const* d_in, const int* in_sizes, int n_in,
                              void* d_out, int out_size, void* d_ws, size_t ws_size,
                              hipStream_t stream) {
  (void)in_sizes; (void)n_in; (void)out_size; (void)d_ws; (void)ws_size;
  const int*   x   = (const int*)d_in[0];
  const float* emb = (const float*)d_in[1];
  const float* Wfx = (const float*)d_in[2];
  const float* Wfh = (const float*)d_in[3];
  const float* bf_ = (const float*)d_in[4];
  const float* Wix = (const float*)d_in[5];
  const float* Wih = (const float*)d_in[6];
  const float* bi_ = (const float*)d_in[7];
  const float* Wgx = (const float*)d_in[8];
  const float* Wgh = (const float*)d_in[9];
  const float* bg_ = (const float*)d_in[10];
  const float* Wox = (const float*)d_in[11];
  const float* Woh = (const float*)d_in[12];
  const float* bo_ = (const float*)d_in[13];
  const float* Wph = (const float*)d_in[14];
  const float* Wpb = (const float*)d_in[15];

  hipLaunchKernelGGL(lstm_rowblock, dim3(128), dim3(1024), 0, stream,
      x, emb, Wfx, Wfh, bf_, Wix, Wih, bi_, Wgx, Wgh, bg_, Wox, Woh, bo_,
      Wph, Wpb, (float*)d_out);
}

// Round 5
// 3138.804 us; speedup vs baseline: 13.6692x; 13.6692x over previous
//
#include <hip/hip_runtime.h>

#define TT 1024
#define HH 256
#define EE 64
#define NC 10
#define SCA __HIP_MEMORY_SCOPE_AGENT

// 256 blocks = 128 rows x 2 halves. Pair (r, r+128) shares an XCD (128%8==0).
// Block (row, hf): j-cols [hf*128, hf*128+128), all 4 gates, full k=256, fp32.
//   f,i,g weights: VGPRs (192/thread). o weights: LDS, lane-linear (128KB).
// Step: poll peer flag -> issue peer-h L3 loads -> phase1 GEMV over OWN k
// (own k-range == own j-range, h in LDS) hides the L3 latency -> stage peer h
// -> phase2 GEMV -> kq shfl-reduce -> gates -> store h (LDS + scoped L3) ->
// barrier (drains stores) -> flag++.  Sync ops = R2's proven pattern.
// ws: flags 256x128B [0,32768) | hx 2 slots x 128 rows x 2 halves x 128 f32.

#define PHASE(PH, HBUF)                                                   \
  do {                                                                    \
    const float* hb_ = (HBUF) + kq * 36;                                  \
    _Pragma("unroll")                                                     \
    for (int ib = 0; ib < 8; ++ib) {                                      \
      const float4 hv = *(const float4*)(hb_ + ib * 4);                   \
      const float4 wo4 =                                                  \
          *(const float4*)&wo_l[((w * 16 + (PH)*8 + ib) * 64 + l) * 4];   \
      af = fmaf(hv.x, wf[(PH)*32 + ib * 4 + 0], af);                      \
      af = fmaf(hv.y, wf[(PH)*32 + ib * 4 + 1], af);                      \
      af = fmaf(hv.z, wf[(PH)*32 + ib * 4 + 2], af);                      \
      af = fmaf(hv.w, wf[(PH)*32 + ib * 4 + 3], af);                      \
      ai = fmaf(hv.x, wi[(PH)*32 + ib * 4 + 0], ai);                      \
      ai = fmaf(hv.y, wi[(PH)*32 + ib * 4 + 1], ai);                      \
      ai = fmaf(hv.z, wi[(PH)*32 + ib * 4 + 2], ai);                      \
      ai = fmaf(hv.w, wi[(PH)*32 + ib * 4 + 3], ai);                      \
      ag = fmaf(hv.x, wg[(PH)*32 + ib * 4 + 0], ag);                      \
      ag = fmaf(hv.y, wg[(PH)*32 + ib * 4 + 1], ag);                      \
      ag = fmaf(hv.z, wg[(PH)*32 + ib * 4 + 2], ag);                      \
      ag = fmaf(hv.w, wg[(PH)*32 + ib * 4 + 3], ag);                      \
      ao = fmaf(hv.x, wo4.x, ao);                                         \
      ao = fmaf(hv.y, wo4.y, ao);                                         \
      ao = fmaf(hv.z, wo4.z, ao);                                         \
      ao = fmaf(hv.w, wo4.w, ao);                                         \
    }                                                                     \
  } while (0)

__global__ __launch_bounds__(512, 2) void lstm_pair(
    const int* __restrict__ x, const float* __restrict__ emb,
    const float* __restrict__ Wfx, const float* __restrict__ Wfh, const float* __restrict__ bf_,
    const float* __restrict__ Wix, const float* __restrict__ Wih, const float* __restrict__ bi_,
    const float* __restrict__ Wgx, const float* __restrict__ Wgh, const float* __restrict__ bg_,
    const float* __restrict__ Wox, const float* __restrict__ Woh, const float* __restrict__ bo_,
    const float* __restrict__ Wph, const float* __restrict__ Wpb,
    unsigned int* __restrict__ flags, float* __restrict__ hx,
    float* __restrict__ out)
{
  const int tid  = threadIdx.x;
  const int bid  = blockIdx.x;
  const int row  = bid & 127;
  const int hf   = bid >> 7;            // half 0/1
  const int j0   = hf * 128;
  const int jloc = tid >> 2;            // 0..127
  const int kq   = tid & 3;             // k-quarter within a 128-half
  const int jglob = j0 + jloc;
  const int w = tid >> 6, l = tid & 63;
  const int kb_own  = hf * 128;
  const int kb_peer = 128 - hf * 128;

  __shared__ __align__(16) float wo_l[32768];   // [w][ib16][l][4] lane-linear
  __shared__ __align__(16) float hown[2][144];  // padded: idx k + (k>>5)*4
  __shared__ __align__(16) float hpeer[144];
  __shared__ float xp[3 * 4 * 128];             // [v][gate][jloc], bias folded
  __shared__ int   xs[TT];
  __shared__ float pj[NC];

  unsigned int* myflag = flags + (row * 2 + hf) * 32;
  unsigned int* pflag  = flags + (row * 2 + (1 - hf)) * 32;

  for (int i2 = tid; i2 < TT; i2 += 512) xs[i2] = x[row * TT + i2];

  // x-projection: 3 vocab x 4 gates x 128 local cols (fp32 exact)
  for (int idx = tid; idx < 1536; idx += 512) {
    int v = idx >> 9, r = idx & 511, g = r >> 7, jl = r & 127;
    const float* Wx = (g == 0) ? Wfx : (g == 1) ? Wix : (g == 2) ? Wgx : Wox;
    const float* bb = (g == 0) ? bf_ : (g == 1) ? bi_ : (g == 2) ? bg_ : bo_;
    float a = bb[j0 + jl];
    const float* ev = emb + v * EE;
#pragma unroll 16
    for (int e = 0; e < EE; ++e) a = fmaf(ev[e], Wx[e * HH + j0 + jl], a);
    xp[idx] = a;
  }

  // weights: i<32 -> own k-half, i>=32 -> peer k-half (matches PHASE order)
  float wf[64], wi[64], wg[64];
#pragma unroll
  for (int i = 0; i < 64; ++i) {
    const int k = ((i & 32) ? kb_peer : kb_own) + kq * 32 + (i & 31);
    wf[i] = Wfh[k * HH + jglob];
    wi[i] = Wih[k * HH + jglob];
    wg[i] = Wgh[k * HH + jglob];
    wo_l[((w * 16 + (i >> 2)) * 64 + l) * 4 + (i & 3)] = Woh[k * HH + jglob];
  }

  if (tid < 144) { hown[0][tid] = 0.f; hown[1][tid] = 0.f; }
  float creg = 0.f;
  __syncthreads();

  for (int t = 0; t < TT; ++t) {
    const int rb = t & 1;          // hown read buf (holds own h(t-1))
    const int sp = rb ^ 1;         // hx slot holding h(t-1)

    if (tid == 0) {
      while (__hip_atomic_load(pflag, __ATOMIC_RELAXED, SCA) < (unsigned)t) { }
    }
    __syncthreads();               // B1: peer h(t-1) visible at L3

    float pv = 0.f;                // issue peer-half load early; hides under phase1
    if (tid < 128)
      pv = __hip_atomic_load(&hx[((sp * 128 + row) * 2 + (1 - hf)) * 128 + tid],
                             __ATOMIC_RELAXED, SCA);

    float af = 0.f, ai = 0.f, ag = 0.f, ao = 0.f;
    PHASE(0, &hown[rb][0]);        // own k-half from local LDS

    if (tid < 128) hpeer[tid + ((tid >> 5) << 2)] = pv;
    __syncthreads();               // B2: hpeer staged

    PHASE(1, hpeer);               // peer k-half

    af += __shfl_xor(af, 1, 64); af += __shfl_xor(af, 2, 64);
    ai += __shfl_xor(ai, 1, 64); ai += __shfl_xor(ai, 2, 64);
    ag += __shfl_xor(ag, 1, 64); ag += __shfl_xor(ag, 2, 64);
    ao += __shfl_xor(ao, 1, 64); ao += __shfl_xor(ao, 2, 64);

    // gates (replicated across kq; identical values -> only kq==0 writes)
    {
      const int v = xs[t];
      const float* xb = xp + v * 512 + jloc;
      float pf = af + xb[0];
      float pi = ai + xb[128];
      float pg = ag + xb[256];
      float po = ao + xb[384];
      float f  = __fdividef(1.f, 1.f + __expf(-pf));
      float i2 = __fdividef(1.f, 1.f + __expf(-pi));
      float o  = __fdividef(1.f, 1.f + __expf(-po));
      float gx = fminf(15.f, fmaxf(-15.f, pg));
      float eg = __expf(2.f * gx);
      float g  = __fdividef(eg - 1.f, eg + 1.f);
      creg = f * creg + i2 * g;
      float cx = fminf(15.f, fmaxf(-15.f, creg));
      float ec = __expf(2.f * cx);
      float th = __fdividef(ec - 1.f, ec + 1.f);
      float hval = th * o;
      if (kq == 0) {
        hown[rb ^ 1][jloc + ((jloc >> 5) << 2)] = hval;
        __hip_atomic_store(&hx[((rb * 128 + row) * 2 + hf) * 128 + jloc],
                           hval, __ATOMIC_RELAXED, SCA);
      }
    }
    __syncthreads();               // B3: drains all scoped h stores (vmcnt0/wave)
    if (tid == 0)
      __hip_atomic_fetch_add(myflag, 1u, __ATOMIC_RELAXED, SCA);
  }

  // ---- final projection + log_softmax on half-0 blocks ----
  if (hf != 0) return;
  if (tid == 0) {
    while (__hip_atomic_load(pflag, __ATOMIC_RELAXED, SCA) < (unsigned)TT) { }
  }
  __syncthreads();
  if (tid < 128) {                 // peer final half: h(1023) lives in slot 1
    float pv = __hip_atomic_load(&hx[((1 * 128 + row) * 2 + 1) * 128 + tid],
                                 __ATOMIC_RELAXED, SCA);
    hpeer[tid + ((tid >> 5) << 2)] = pv;
  }
  __syncthreads();
  if (tid < NC) {                  // own final half in hown[0] (t=1023: rb^1=0)
    float a = Wpb[tid];
    for (int k = 0; k < 128; ++k)
      a = fmaf(hown[0][k + ((k >> 5) << 2)], Wph[k * NC + tid], a);
    for (int k = 0; k < 128; ++k)
      a = fmaf(hpeer[k + ((k >> 5) << 2)], Wph[(128 + k) * NC + tid], a);
    pj[tid] = a;
  }
  __syncthreads();
  if (tid < NC) {
    float m = pj[0];
#pragma unroll
    for (int c2 = 1; c2 < NC; ++c2) m = fmaxf(m, pj[c2]);
    float s = 0.f;
#pragma unroll
    for (int c2 = 0; c2 < NC; ++c2) s += __expf(pj[c2] - m);
    out[row * NC + tid] = pj[tid] - m - __logf(s);
  }
}

extern "C" void kernel_launch(void* const* d_in, const int* in_sizes, int n_in,
                              void* d_out, int out_size, void* d_ws, size_t ws_size,
                              hipStream_t stream) {
  (void)in_sizes; (void)n_in; (void)out_size; (void)ws_size;
  const int*   x   = (const int*)d_in[0];
  const float* emb = (const float*)d_in[1];
  const float* Wfx = (const float*)d_in[2];
  const float* Wfh = (const float*)d_in[3];
  const float* bf_ = (const float*)d_in[4];
  const float* Wix = (const float*)d_in[5];
  const float* Wih = (const float*)d_in[6];
  const float* bi_ = (const float*)d_in[7];
  const float* Wgx = (const float*)d_in[8];
  const float* Wgh = (const float*)d_in[9];
  const float* bg_ = (const float*)d_in[10];
  const float* Wox = (const float*)d_in[11];
  const float* Woh = (const float*)d_in[12];
  const float* bo_ = (const float*)d_in[13];
  const float* Wph = (const float*)d_in[14];
  const float* Wpb = (const float*)d_in[15];

  unsigned int* flags = (unsigned int*)d_ws;
  float*        hx    = (float*)((char*)d_ws + 32768);

  // zero flags + both hx slots (h(-1)=0); captured -> runs on every replay
  hipMemsetAsync(d_ws, 0, 32768 + 262144, stream);

  hipLaunchKernelGGL(lstm_pair, dim3(256), dim3(512), 0, stream,
      x, emb, Wfx, Wfh, bf_, Wix, Wih, bi_, Wgx, Wgh, bg_, Wox, Woh, bo_,
      Wph, Wpb, flags, hx, (float*)d_out);
}